// Round 6
// baseline (140.622 us; speedup 1.0000x reference)
//
#include <hip/hip_runtime.h>
#include <hip/hip_bf16.h>
#include <math.h>

typedef __bf16 bf16;
typedef bf16 bf16x4 __attribute__((ext_vector_type(4)));
typedef bf16 bf16x8 __attribute__((ext_vector_type(8)));
typedef float f32x4 __attribute__((ext_vector_type(4)));

#define B_   16
#define LQ_  256
#define LK_  4096
#define E_   64
#define H_   4
#define EK_  16
#define D_   32
#define LAT_ 32

// ws layout (bytes)
#define OFF_QP    0u          // bf16 [16][256][64]              = 512 KB
#define OFF_KP    524288u     // bf16 [16][4096][64]             = 8 MB
#define OFF_MVFB  8912896u    // bf16 [16][128][4][64][8] frag-ready = 8 MB
#define OFF_WOT   17301504u   // bf16 [32][128]                  = 8 KB
#define OFF_NDP   17309696u   // f32  [8 kc][16 b][4 h][256 q][64] = 33.5 MB (num 0..31, den 32..63)
#define WS_NEED   50864128u

#define LOG2E 1.44269504f

__device__ inline f32x4 mfma_bf16(bf16x8 a, bf16x8 b, f32x4 c) {
  return __builtin_amdgcn_mfma_f32_16x16x32_bf16(a, b, c, 0, 0, 0);
}
__device__ inline bf16x8 zero8() {
  bf16x8 z;
#pragma unroll
  for (int i = 0; i < 8; ++i) z[i] = (bf16)0.0f;
  return z;
}

// ---------------------------------------------------------------------------
// Kernel 0: prep.  blocks [0,32): q-proj, [32,544): k-proj, [544,800): mvfB,
// [800]: WoT.  Proj = MFMA GEMM rows x (64x64) W, +bias; q scaled by
// 0.25*log2e (folds 1/sqrt(ek) and the exp->exp2 conversion).
// ---------------------------------------------------------------------------
__global__ __launch_bounds__(256) void prep_kernel(
    const float* __restrict__ query, const float* __restrict__ key,
    const float* __restrict__ value, const int* __restrict__ mask,
    const float* __restrict__ Wq, const float* __restrict__ bq,
    const float* __restrict__ Wk, const float* __restrict__ bk,
    const float* __restrict__ Wo,
    bf16* __restrict__ qp, bf16* __restrict__ kp,
    bf16* __restrict__ mvfB, bf16* __restrict__ WoT)
{
  __shared__ __align__(16) bf16 s_b[16896];  // 33792 B, unioned across roles
  const int bid = blockIdx.x;
  const int tid = threadIdx.x;

  if (bid < 544) {
    // ---- projection role: 128 rows per block ----
    const bool isQ = bid < 32;
    const int row0 = isQ ? bid * 128 : (bid - 32) * 128;
    const float* in   = isQ ? query : key;
    const float* W    = isQ ? Wq : Wk;
    const float* bias = isQ ? bq : bk;
    bf16* outp        = isQ ? qp : kp;
    const float scal  = isQ ? (0.25f * LOG2E) : 1.0f;

    bf16* sIn = s_b;          // [128][72]
    bf16* sWT = s_b + 9216;   // [64][72]  (W^T: [col][k])

#pragma unroll
    for (int p = 0; p < 8; ++p) {
      int f4 = tid + p * 256;            // 2048 float4
      int row = f4 >> 4, e4 = (f4 & 15) * 4;
      float4 v = *(const float4*)(in + (size_t)(row0 + row) * 64 + e4);
      bf16x4 b4;
      b4[0] = (bf16)v.x; b4[1] = (bf16)v.y; b4[2] = (bf16)v.z; b4[3] = (bf16)v.w;
      *(bf16x4*)(sIn + row * 72 + e4) = b4;
    }
#pragma unroll
    for (int p = 0; p < 4; ++p) {
      int f4 = tid + p * 256;            // 1024 float4
      int k = f4 >> 4, c4 = (f4 & 15) * 4;
      float4 v = *(const float4*)(W + k * 64 + c4);
      sWT[(c4 + 0) * 72 + k] = (bf16)v.x;
      sWT[(c4 + 1) * 72 + k] = (bf16)v.y;
      sWT[(c4 + 2) * 72 + k] = (bf16)v.z;
      sWT[(c4 + 3) * 72 + k] = (bf16)v.w;
    }
    __syncthreads();

    const int w = tid >> 6, l = tid & 63, l15 = l & 15, g = l >> 4;
    f32x4 acc[2][4];
#pragma unroll
    for (int mt = 0; mt < 2; ++mt)
#pragma unroll
      for (int nt = 0; nt < 4; ++nt) acc[mt][nt] = f32x4{0.f, 0.f, 0.f, 0.f};

#pragma unroll
    for (int ks = 0; ks < 2; ++ks) {
      bf16x8 A0 = *(bf16x8*)(sIn + (32 * w + l15) * 72 + 32 * ks + 8 * g);
      bf16x8 A1 = *(bf16x8*)(sIn + (32 * w + 16 + l15) * 72 + 32 * ks + 8 * g);
#pragma unroll
      for (int nt = 0; nt < 4; ++nt) {
        bf16x8 Bf = *(bf16x8*)(sWT + (16 * nt + l15) * 72 + 32 * ks + 8 * g);
        acc[0][nt] = mfma_bf16(A0, Bf, acc[0][nt]);
        acc[1][nt] = mfma_bf16(A1, Bf, acc[1][nt]);
      }
    }
#pragma unroll
    for (int mt = 0; mt < 2; ++mt)
#pragma unroll
      for (int nt = 0; nt < 4; ++nt) {
        int col = 16 * nt + l15;
        float bv = bias[col];
#pragma unroll
        for (int r = 0; r < 4; ++r) {
          int row = row0 + 32 * w + 16 * mt + 4 * g + r;
          outp[(size_t)row * 64 + col] = (bf16)((acc[mt][nt][r] + bv) * scal);
        }
      }
  } else if (bid < 800) {
    // ---- mvfB role: 256-kk chunk -> bf16, B-frag-ready tiled layout ----
    // element (b,col,kk): tile=kk>>5, nt=col>>4, lane=16*((kk>>3)&3)+(col&15),
    // j=kk&7 -> flat (((b*128+tile)*4+nt)*64+lane)*8+j
    const int rb = bid - 544;
    const int b = rb >> 4, kk0 = (rb & 15) * 256;
    // s_b as [col 64][kk 256 pad 264]
#pragma unroll
    for (int p = 0; p < 8; ++p) {
      int f4 = tid + p * 256;            // 2048 vec4 over [256 kk][32 d]
      int kk = f4 >> 3, d4 = (f4 & 7) * 4;
      size_t gi = ((size_t)(b * LK_ + kk0 + kk)) * 32 + d4;
      float4 v = *(const float4*)(value + gi);
      int4   m = *(const int4*)(mask + gi);
      s_b[(d4 + 0) * 264 + kk] = (bf16)(m.x ? v.x : 0.0f);
      s_b[(d4 + 1) * 264 + kk] = (bf16)(m.y ? v.y : 0.0f);
      s_b[(d4 + 2) * 264 + kk] = (bf16)(m.z ? v.z : 0.0f);
      s_b[(d4 + 3) * 264 + kk] = (bf16)(m.w ? v.w : 0.0f);
      s_b[(32 + d4 + 0) * 264 + kk] = (bf16)(float)m.x;
      s_b[(32 + d4 + 1) * 264 + kk] = (bf16)(float)m.y;
      s_b[(32 + d4 + 2) * 264 + kk] = (bf16)(float)m.z;
      s_b[(32 + d4 + 3) * 264 + kk] = (bf16)(float)m.w;
    }
    __syncthreads();
    // writeback: thread owns col = tid>>2, kk range [seg*64, seg*64+64)
    const int col = tid >> 2, seg = tid & 3;
    const int nt = col >> 4, l15c = col & 15;
#pragma unroll
    for (int w2 = 0; w2 < 8; ++w2) {
      int kkg = seg * 64 + w2 * 8;                 // 8-aligned
      int tile = (kk0 + kkg) >> 5;
      int gq = (kkg >> 3) & 3;
      int lane = 16 * gq + l15c;
      uint4 d = *(uint4*)(s_b + col * 264 + kkg);
      *(uint4*)(mvfB + (size_t)((((b * 128 + tile) * 4 + nt) * 64 + lane)) * 8) = d;
    }
  } else {
    // ---- WoT role: Wo[128][32] -> WoT[32][128] bf16 ----
#pragma unroll
    for (int p = 0; p < 16; ++p) {
      int f = tid + p * 256;
      int k = f >> 5, n = f & 31;
      WoT[n * 128 + k] = (bf16)Wo[f];
    }
  }
}

// ---------------------------------------------------------------------------
// Kernel 1: attention — barrier-free, atomic-free, MAX OCCUPANCY. grid 2048:
// kc=bid&7 (512 kk), qt=(bid>>3)&15 (16 q), b=bid>>7. 4 waves = 4 heads.
// 8 blocks/CU = 32 waves/CU (q-tile 16 halves per-wave state vs q-tile 32;
// total MFMA/exp2/ndp work is invariant — only kp re-reads double, L2-hit).
// Per 32-kk tile: transposed scores MFMA (K padded 16->32), exp2 -> bf16
// wave-private LDS, PV MFMAs vs frag-ready mvfB. Plain stores of kc-partials.
// ---------------------------------------------------------------------------
__global__ __launch_bounds__(256, 8) void attn_kernel(
    const bf16* __restrict__ qp, const bf16* __restrict__ kp,
    const bf16* __restrict__ mvfB, float* __restrict__ ndp)
{
  __shared__ __align__(16) bf16 s_se[4 * 640];   // [wave][q 16 stride 40][kk 32]

  const int bid = blockIdx.x;
  const int kc = bid & 7, qt = (bid >> 3) & 15, b = bid >> 7;
  const int tid = threadIdx.x;
  const int h = tid >> 6, l = tid & 63, l15 = l & 15, g = l >> 4;
  const int q0 = qt * 16;
  const int tile0 = kc * 16;   // tiles of 32 kk; 16 per block

  // persistent Q B-frag (n = q, k = e; k 16..31 zero-padded)
  bf16x8 qB;
  if (l < 32) {
    qB = *(const bf16x8*)(qp + (size_t)((b * LQ_ + q0 + l15) * 64 + h * EK_ + g * 8));
  } else { qB = zero8(); }

  f32x4 acc[4];
#pragma unroll
  for (int nt = 0; nt < 4; ++nt) acc[nt] = f32x4{0.f, 0.f, 0.f, 0.f};

  bf16* se_w = s_se + h * 640;
  const bf16* mvt0 = mvfB + (size_t)(b * 128 + tile0) * 2048;  // 4*64*8 per tile
  const bf16* kp_b = kp + (size_t)(b * LK_ + tile0 * 32) * 64 + h * EK_ + g * 8;

#pragma unroll 2
  for (int t = 0; t < 16; ++t) {
    const bf16* mvt = mvt0 + (size_t)t * 2048;

    // global loads -> regs (no LDS staging, no barriers)
    bf16x8 mvB[4];
#pragma unroll
    for (int nt = 0; nt < 4; ++nt)
      mvB[nt] = *(const bf16x8*)(mvt + (nt * 64 + l) * 8);

    bf16x8 kA0, kA1;
    if (l < 32) {
      kA0 = *(const bf16x8*)(kp_b + (size_t)(t * 32 + l15) * 64);
      kA1 = *(const bf16x8*)(kp_b + (size_t)(t * 32 + 16 + l15) * 64);
    } else { kA0 = zero8(); kA1 = zero8(); }

    // transposed scores: S^T[kk][q] (m = kk-local, n = q-local)
    f32x4 S0 = mfma_bf16(kA0, qB, f32x4{0.f, 0.f, 0.f, 0.f});
    f32x4 S1 = mfma_bf16(kA1, qB, f32x4{0.f, 0.f, 0.f, 0.f});

    // exp2 (log2e folded into qp) -> bf16, packed b64 writes
    bf16x4 e0, e1;
#pragma unroll
    for (int r = 0; r < 4; ++r) { e0[r] = (bf16)exp2f(S0[r]); e1[r] = (bf16)exp2f(S1[r]); }
    *(bf16x4*)(se_w + l15 * 40 + 4 * g)      = e0;   // kk = 4g+r
    *(bf16x4*)(se_w + l15 * 40 + 16 + 4 * g) = e1;   // kk = 16+4g+r

    // ordering fence for the same-wave LDS round-trip (no barrier needed)
    asm volatile("" ::: "memory");

    // PV A-frag from wave-private LDS: A[q=l15][kk=8g+j]
    bf16x8 eA = *(bf16x8*)(se_w + l15 * 40 + 8 * g);

#pragma unroll
    for (int nt = 0; nt < 4; ++nt)
      acc[nt] = mfma_bf16(eA, mvB[nt], acc[nt]);
  }

  // epilogue: plain stores of this block's kc-partial (disjoint slice)
  float* ndp_w = ndp + ((((size_t)kc * B_ + b) * H_ + h) * LQ_) * 64;
#pragma unroll
  for (int nt = 0; nt < 4; ++nt)
#pragma unroll
    for (int r = 0; r < 4; ++r) {
      int q = q0 + 4 * g + r;
      int col = 16 * nt + l15;
      ndp_w[(size_t)q * 64 + col] = acc[nt][r];
    }
}

// ---------------------------------------------------------------------------
// Kernel 2: reduce 8 kc-partials, x = num/den -> bf16 -> out = x @ Wo + bo.
// grid 256 (b, 16-q tile).
// ---------------------------------------------------------------------------
__global__ __launch_bounds__(256) void out_kernel(
    const float* __restrict__ ndp, const bf16* __restrict__ WoT,
    const float* __restrict__ bo, float* __restrict__ out)
{
  __shared__ __align__(16) bf16 s_x[16 * 136];  // [q 16][j 128 pad 136]
  const int bid = blockIdx.x;
  const int b = bid >> 4, q0 = (bid & 15) * 16;
  const int tid = threadIdx.x;
  const int q = tid >> 4, jg = tid & 15;
  const int h = jg >> 2, d0 = (jg & 3) * 8;

  f32x4 nlo = f32x4{0.f,0.f,0.f,0.f}, nhi = f32x4{0.f,0.f,0.f,0.f};
  f32x4 dlo = f32x4{0.f,0.f,0.f,0.f}, dhi = f32x4{0.f,0.f,0.f,0.f};
#pragma unroll
  for (int kc = 0; kc < 8; ++kc) {
    const float* p = ndp + ((((size_t)kc * B_ + b) * H_ + h) * LQ_ + q0 + q) * 64;
    nlo += *(const f32x4*)(p + d0);
    nhi += *(const f32x4*)(p + d0 + 4);
    dlo += *(const f32x4*)(p + 32 + d0);
    dhi += *(const f32x4*)(p + 32 + d0 + 4);
  }
  bf16* sx = s_x + q * 136 + h * 32 + d0;
#pragma unroll
  for (int i = 0; i < 4; ++i) {
    sx[i]     = (bf16)(nlo[i] / dlo[i]);
    sx[4 + i] = (bf16)(nhi[i] / dhi[i]);
  }
  __syncthreads();
  const int w = tid >> 6, l = tid & 63, l15 = l & 15, g = l >> 4;
  if (w < 2) {
    const int nt = w;
    f32x4 acc = f32x4{0.f, 0.f, 0.f, 0.f};
#pragma unroll
    for (int ks = 0; ks < 4; ++ks) {
      bf16x8 A  = *(bf16x8*)(s_x + l15 * 136 + 32 * ks + 8 * g);
      bf16x8 Bf = *(const bf16x8*)(WoT + (l15 + 16 * nt) * 128 + 32 * ks + 8 * g);
      acc = mfma_bf16(A, Bf, acc);
    }
    float bv = bo[l15 + 16 * nt];
#pragma unroll
    for (int r = 0; r < 4; ++r) {
      int row = q0 + 4 * g + r;
      out[(size_t)(b * LQ_ + row) * LAT_ + l15 + 16 * nt] = acc[r] + bv;
    }
  }
}

extern "C" void kernel_launch(void* const* d_in, const int* in_sizes, int n_in,
                              void* d_out, int out_size, void* d_ws, size_t ws_size,
                              hipStream_t stream) {
  const float* query = (const float*)d_in[0];
  const float* key   = (const float*)d_in[1];
  const float* value = (const float*)d_in[2];
  const int*   mask  = (const int*)d_in[3];
  const float* Wq    = (const float*)d_in[4];
  const float* bq    = (const float*)d_in[5];
  const float* Wk    = (const float*)d_in[6];
  const float* bk    = (const float*)d_in[7];
  const float* Wo    = (const float*)d_in[8];
  const float* bo    = (const float*)d_in[9];
  float* out = (float*)d_out;
  char* ws = (char*)d_ws;

  if (ws_size < (size_t)WS_NEED) return;  // diagnostic: leaves out == 0

  bf16* qp   = (bf16*)(ws + OFF_QP);
  bf16* kp   = (bf16*)(ws + OFF_KP);
  bf16* mvfB = (bf16*)(ws + OFF_MVFB);
  bf16* WoT  = (bf16*)(ws + OFF_WOT);
  float* ndp = (float*)(ws + OFF_NDP);

  prep_kernel<<<801, 256, 0, stream>>>(query, key, value, mask, Wq, bq, Wk, bk,
                                       Wo, qp, kp, mvfB, WoT);
  attn_kernel<<<2048, 256, 0, stream>>>(qp, kp, mvfB, ndp);
  out_kernel<<<256, 256, 0, stream>>>(ndp, WoT, bo, out);
}

// Round 7
// 131.135 us; speedup vs baseline: 1.0723x; 1.0723x over previous
//
#include <hip/hip_runtime.h>
#include <hip/hip_bf16.h>
#include <math.h>

typedef __bf16 bf16;
typedef bf16 bf16x4 __attribute__((ext_vector_type(4)));
typedef bf16 bf16x8 __attribute__((ext_vector_type(8)));
typedef float f32x4 __attribute__((ext_vector_type(4)));

#define B_   16
#define LQ_  256
#define LK_  4096
#define E_   64
#define H_   4
#define EK_  16
#define D_   32
#define LAT_ 32

// ws layout (bytes)
#define OFF_QP    0u          // bf16 [16][256][64]              = 512 KB
#define OFF_KP    524288u     // bf16 [16][4096][64]             = 8 MB
#define OFF_MVFB  8912896u    // bf16 [16][128][4][64][8] frag-ready = 8 MB
#define OFF_WOT   17301504u   // bf16 [32][128]                  = 8 KB
#define OFF_NDP   17309696u   // f32  [8 kc][16 b][4 h][256 q][64] = 33.5 MB (num 0..31, den 32..63)
#define WS_NEED   50864128u

#define LOG2E 1.44269504f

__device__ inline f32x4 mfma_bf16(bf16x8 a, bf16x8 b, f32x4 c) {
  return __builtin_amdgcn_mfma_f32_16x16x32_bf16(a, b, c, 0, 0, 0);
}
__device__ inline bf16x8 zero8() {
  bf16x8 z;
#pragma unroll
  for (int i = 0; i < 8; ++i) z[i] = (bf16)0.0f;
  return z;
}

// ---------------------------------------------------------------------------
// Kernel 0: prep.  blocks [0,32): q-proj, [32,544): k-proj, [544,800): mvfB,
// [800]: WoT.  Proj = MFMA GEMM rows x (64x64) W, +bias; q scaled by
// 0.25*log2e (folds 1/sqrt(ek) and the exp->exp2 conversion).
// ---------------------------------------------------------------------------
__global__ __launch_bounds__(256) void prep_kernel(
    const float* __restrict__ query, const float* __restrict__ key,
    const float* __restrict__ value, const int* __restrict__ mask,
    const float* __restrict__ Wq, const float* __restrict__ bq,
    const float* __restrict__ Wk, const float* __restrict__ bk,
    const float* __restrict__ Wo,
    bf16* __restrict__ qp, bf16* __restrict__ kp,
    bf16* __restrict__ mvfB, bf16* __restrict__ WoT)
{
  __shared__ __align__(16) bf16 s_b[16896];  // 33792 B, unioned across roles
  const int bid = blockIdx.x;
  const int tid = threadIdx.x;

  if (bid < 544) {
    // ---- projection role: 128 rows per block ----
    const bool isQ = bid < 32;
    const int row0 = isQ ? bid * 128 : (bid - 32) * 128;
    const float* in   = isQ ? query : key;
    const float* W    = isQ ? Wq : Wk;
    const float* bias = isQ ? bq : bk;
    bf16* outp        = isQ ? qp : kp;
    const float scal  = isQ ? (0.25f * LOG2E) : 1.0f;

    bf16* sIn = s_b;          // [128][72]
    bf16* sWT = s_b + 9216;   // [64][72]  (W^T: [col][k])

#pragma unroll
    for (int p = 0; p < 8; ++p) {
      int f4 = tid + p * 256;            // 2048 float4
      int row = f4 >> 4, e4 = (f4 & 15) * 4;
      float4 v = *(const float4*)(in + (size_t)(row0 + row) * 64 + e4);
      bf16x4 b4;
      b4[0] = (bf16)v.x; b4[1] = (bf16)v.y; b4[2] = (bf16)v.z; b4[3] = (bf16)v.w;
      *(bf16x4*)(sIn + row * 72 + e4) = b4;
    }
#pragma unroll
    for (int p = 0; p < 4; ++p) {
      int f4 = tid + p * 256;            // 1024 float4
      int k = f4 >> 4, c4 = (f4 & 15) * 4;
      float4 v = *(const float4*)(W + k * 64 + c4);
      sWT[(c4 + 0) * 72 + k] = (bf16)v.x;
      sWT[(c4 + 1) * 72 + k] = (bf16)v.y;
      sWT[(c4 + 2) * 72 + k] = (bf16)v.z;
      sWT[(c4 + 3) * 72 + k] = (bf16)v.w;
    }
    __syncthreads();

    const int w = tid >> 6, l = tid & 63, l15 = l & 15, g = l >> 4;
    f32x4 acc[2][4];
#pragma unroll
    for (int mt = 0; mt < 2; ++mt)
#pragma unroll
      for (int nt = 0; nt < 4; ++nt) acc[mt][nt] = f32x4{0.f, 0.f, 0.f, 0.f};

#pragma unroll
    for (int ks = 0; ks < 2; ++ks) {
      bf16x8 A0 = *(bf16x8*)(sIn + (32 * w + l15) * 72 + 32 * ks + 8 * g);
      bf16x8 A1 = *(bf16x8*)(sIn + (32 * w + 16 + l15) * 72 + 32 * ks + 8 * g);
#pragma unroll
      for (int nt = 0; nt < 4; ++nt) {
        bf16x8 Bf = *(bf16x8*)(sWT + (16 * nt + l15) * 72 + 32 * ks + 8 * g);
        acc[0][nt] = mfma_bf16(A0, Bf, acc[0][nt]);
        acc[1][nt] = mfma_bf16(A1, Bf, acc[1][nt]);
      }
    }
#pragma unroll
    for (int mt = 0; mt < 2; ++mt)
#pragma unroll
      for (int nt = 0; nt < 4; ++nt) {
        int col = 16 * nt + l15;
        float bv = bias[col];
#pragma unroll
        for (int r = 0; r < 4; ++r) {
          int row = row0 + 32 * w + 16 * mt + 4 * g + r;
          outp[(size_t)row * 64 + col] = (bf16)((acc[mt][nt][r] + bv) * scal);
        }
      }
  } else if (bid < 800) {
    // ---- mvfB role: 256-kk chunk -> bf16, B-frag-ready tiled layout ----
    // element (b,col,kk): tile=kk>>5, nt=col>>4, lane=16*((kk>>3)&3)+(col&15),
    // j=kk&7 -> flat (((b*128+tile)*4+nt)*64+lane)*8+j
    const int rb = bid - 544;
    const int b = rb >> 4, kk0 = (rb & 15) * 256;
    // s_b as [col 64][kk 256 pad 264]
#pragma unroll
    for (int p = 0; p < 8; ++p) {
      int f4 = tid + p * 256;            // 2048 vec4 over [256 kk][32 d]
      int kk = f4 >> 3, d4 = (f4 & 7) * 4;
      size_t gi = ((size_t)(b * LK_ + kk0 + kk)) * 32 + d4;
      float4 v = *(const float4*)(value + gi);
      int4   m = *(const int4*)(mask + gi);
      s_b[(d4 + 0) * 264 + kk] = (bf16)(m.x ? v.x : 0.0f);
      s_b[(d4 + 1) * 264 + kk] = (bf16)(m.y ? v.y : 0.0f);
      s_b[(d4 + 2) * 264 + kk] = (bf16)(m.z ? v.z : 0.0f);
      s_b[(d4 + 3) * 264 + kk] = (bf16)(m.w ? v.w : 0.0f);
      s_b[(32 + d4 + 0) * 264 + kk] = (bf16)(float)m.x;
      s_b[(32 + d4 + 1) * 264 + kk] = (bf16)(float)m.y;
      s_b[(32 + d4 + 2) * 264 + kk] = (bf16)(float)m.z;
      s_b[(32 + d4 + 3) * 264 + kk] = (bf16)(float)m.w;
    }
    __syncthreads();
    // writeback: thread owns col = tid>>2, kk range [seg*64, seg*64+64)
    const int col = tid >> 2, seg = tid & 3;
    const int nt = col >> 4, l15c = col & 15;
#pragma unroll
    for (int w2 = 0; w2 < 8; ++w2) {
      int kkg = seg * 64 + w2 * 8;                 // 8-aligned
      int tile = (kk0 + kkg) >> 5;
      int gq = (kkg >> 3) & 3;
      int lane = 16 * gq + l15c;
      uint4 d = *(uint4*)(s_b + col * 264 + kkg);
      *(uint4*)(mvfB + (size_t)((((b * 128 + tile) * 4 + nt) * 64 + lane)) * 8) = d;
    }
  } else {
    // ---- WoT role: Wo[128][32] -> WoT[32][128] bf16 ----
#pragma unroll
    for (int p = 0; p < 16; ++p) {
      int f = tid + p * 256;
      int k = f >> 5, n = f & 31;
      WoT[n * 128 + k] = (bf16)Wo[f];
    }
  }
}

// ---------------------------------------------------------------------------
// Kernel 1: attention, q-tile 64 — max load amortization. grid 512: kc=bid&7
// (512 kk), qt=(bid>>3)&3 (64 q), b=bid>>5. 4 waves = 4 heads, barrier-free,
// atomic-free. Per 32-kk tile per wave: 6 global loads feed 24 MFMAs
// (8 score + 16 PV) — half the total VMEM instrs of R4's q32, quarter of
// R6's q16 (R5/R6 showed time tracks load count, not occupancy). Explicit
// next-tile prefetch of mvB/kA; VGPR-generous launch_bounds (R6's cap of 64
// serialized the loop). exp2 -> bf16 wave-private LDS -> PV A-frags.
// ---------------------------------------------------------------------------
__global__ __launch_bounds__(256, 2) void attn_kernel(
    const bf16* __restrict__ qp, const bf16* __restrict__ kp,
    const bf16* __restrict__ mvfB, float* __restrict__ ndp)
{
  __shared__ __align__(16) bf16 s_se[4 * 2560];   // [wave][q 64 stride 40][kk 32]

  const int bid = blockIdx.x;
  const int kc = bid & 7, qt = (bid >> 3) & 3, b = bid >> 5;
  const int tid = threadIdx.x;
  const int h = tid >> 6, l = tid & 63, l15 = l & 15, g = l >> 4;
  const int q0 = qt * 64;
  const int tile0 = kc * 16;   // tiles of 32 kk; 16 per block

  // persistent Q B-frags (n = q, k = e; k 16..31 zero-padded)
  bf16x8 qB[4];
  if (l < 32) {
#pragma unroll
    for (int nt = 0; nt < 4; ++nt)
      qB[nt] = *(const bf16x8*)(qp + (size_t)((b * LQ_ + q0 + 16 * nt + l15) * 64 + h * EK_ + g * 8));
  } else {
#pragma unroll
    for (int nt = 0; nt < 4; ++nt) qB[nt] = zero8();
  }

  f32x4 acc[4][4];
#pragma unroll
  for (int mq = 0; mq < 4; ++mq)
#pragma unroll
    for (int nt = 0; nt < 4; ++nt) acc[mq][nt] = f32x4{0.f, 0.f, 0.f, 0.f};

  bf16* se_w = s_se + h * 2560;
  const bf16* mvt0 = mvfB + (size_t)(b * 128 + tile0) * 2048;  // 4*64*8 per tile
  const bf16* kp_b = kp + (size_t)(b * LK_ + tile0 * 32) * 64 + h * EK_ + g * 8;

  // prefetch tile 0
  bf16x8 mvB[4], kA0, kA1;
#pragma unroll
  for (int nt = 0; nt < 4; ++nt)
    mvB[nt] = *(const bf16x8*)(mvt0 + (nt * 64 + l) * 8);
  if (l < 32) {
    kA0 = *(const bf16x8*)(kp_b + (size_t)(l15) * 64);
    kA1 = *(const bf16x8*)(kp_b + (size_t)(16 + l15) * 64);
  } else { kA0 = zero8(); kA1 = zero8(); }

  for (int t = 0; t < 16; ++t) {
    // prefetch tile t+1 (wraps at 15 -> reloads tile 0, harmless)
    const int tn = (t + 1) & 15;
    const bf16* mvtn = mvt0 + (size_t)tn * 2048;
    bf16x8 mvBn[4], kA0n, kA1n;
#pragma unroll
    for (int nt = 0; nt < 4; ++nt)
      mvBn[nt] = *(const bf16x8*)(mvtn + (nt * 64 + l) * 8);
    if (l < 32) {
      kA0n = *(const bf16x8*)(kp_b + (size_t)(tn * 32 + l15) * 64);
      kA1n = *(const bf16x8*)(kp_b + (size_t)(tn * 32 + 16 + l15) * 64);
    } else { kA0n = zero8(); kA1n = zero8(); }

    // transposed scores: S^T[kk][q] (m = kk-local, n = q-local), 8 MFMAs
    f32x4 S[2][4];
#pragma unroll
    for (int nt = 0; nt < 4; ++nt) {
      S[0][nt] = mfma_bf16(kA0, qB[nt], f32x4{0.f, 0.f, 0.f, 0.f});
      S[1][nt] = mfma_bf16(kA1, qB[nt], f32x4{0.f, 0.f, 0.f, 0.f});
    }

    // exp2 (log2e folded into qp) -> bf16, packed b64 writes (conflict-free)
#pragma unroll
    for (int mt = 0; mt < 2; ++mt)
#pragma unroll
      for (int nt = 0; nt < 4; ++nt) {
        bf16x4 e4;
#pragma unroll
        for (int r = 0; r < 4; ++r) e4[r] = (bf16)exp2f(S[mt][nt][r]);
        *(bf16x4*)(se_w + (16 * nt + l15) * 40 + 16 * mt + 4 * g) = e4;
      }

    // ordering fence for the same-wave LDS round-trip (no barrier needed)
    asm volatile("" ::: "memory");

    // PV: A-frags from wave-private LDS, 16 MFMAs
#pragma unroll
    for (int mq = 0; mq < 4; ++mq) {
      bf16x8 eA = *(bf16x8*)(se_w + (16 * mq + l15) * 40 + 8 * g);
#pragma unroll
      for (int nt = 0; nt < 4; ++nt)
        acc[mq][nt] = mfma_bf16(eA, mvB[nt], acc[mq][nt]);
    }

    // rotate prefetch
#pragma unroll
    for (int nt = 0; nt < 4; ++nt) mvB[nt] = mvBn[nt];
    kA0 = kA0n; kA1 = kA1n;
  }

  // epilogue: plain stores of this block's kc-partial (disjoint slice)
  float* ndp_w = ndp + ((((size_t)kc * B_ + b) * H_ + h) * LQ_) * 64;
#pragma unroll
  for (int mq = 0; mq < 4; ++mq)
#pragma unroll
    for (int nt = 0; nt < 4; ++nt)
#pragma unroll
      for (int r = 0; r < 4; ++r) {
        int q = q0 + 16 * mq + 4 * g + r;
        int col = 16 * nt + l15;
        ndp_w[(size_t)q * 64 + col] = acc[mq][nt][r];
      }
}

// ---------------------------------------------------------------------------
// Kernel 2: reduce 8 kc-partials, x = num/den -> bf16 -> out = x @ Wo + bo.
// grid 256 (b, 16-q tile).
// ---------------------------------------------------------------------------
__global__ __launch_bounds__(256) void out_kernel(
    const float* __restrict__ ndp, const bf16* __restrict__ WoT,
    const float* __restrict__ bo, float* __restrict__ out)
{
  __shared__ __align__(16) bf16 s_x[16 * 136];  // [q 16][j 128 pad 136]
  const int bid = blockIdx.x;
  const int b = bid >> 4, q0 = (bid & 15) * 16;
  const int tid = threadIdx.x;
  const int q = tid >> 4, jg = tid & 15;
  const int h = jg >> 2, d0 = (jg & 3) * 8;

  f32x4 nlo = f32x4{0.f,0.f,0.f,0.f}, nhi = f32x4{0.f,0.f,0.f,0.f};
  f32x4 dlo = f32x4{0.f,0.f,0.f,0.f}, dhi = f32x4{0.f,0.f,0.f,0.f};
#pragma unroll
  for (int kc = 0; kc < 8; ++kc) {
    const float* p = ndp + ((((size_t)kc * B_ + b) * H_ + h) * LQ_ + q0 + q) * 64;
    nlo += *(const f32x4*)(p + d0);
    nhi += *(const f32x4*)(p + d0 + 4);
    dlo += *(const f32x4*)(p + 32 + d0);
    dhi += *(const f32x4*)(p + 32 + d0 + 4);
  }
  bf16* sx = s_x + q * 136 + h * 32 + d0;
#pragma unroll
  for (int i = 0; i < 4; ++i) {
    sx[i]     = (bf16)(nlo[i] / dlo[i]);
    sx[4 + i] = (bf16)(nhi[i] / dhi[i]);
  }
  __syncthreads();
  const int w = tid >> 6, l = tid & 63, l15 = l & 15, g = l >> 4;
  if (w < 2) {
    const int nt = w;
    f32x4 acc = f32x4{0.f, 0.f, 0.f, 0.f};
#pragma unroll
    for (int ks = 0; ks < 4; ++ks) {
      bf16x8 A  = *(bf16x8*)(s_x + l15 * 136 + 32 * ks + 8 * g);
      bf16x8 Bf = *(const bf16x8*)(WoT + (l15 + 16 * nt) * 128 + 32 * ks + 8 * g);
      acc = mfma_bf16(A, Bf, acc);
    }
    float bv = bo[l15 + 16 * nt];
#pragma unroll
    for (int r = 0; r < 4; ++r) {
      int row = q0 + 4 * g + r;
      out[(size_t)(b * LQ_ + row) * LAT_ + l15 + 16 * nt] = acc[r] + bv;
    }
  }
}

extern "C" void kernel_launch(void* const* d_in, const int* in_sizes, int n_in,
                              void* d_out, int out_size, void* d_ws, size_t ws_size,
                              hipStream_t stream) {
  const float* query = (const float*)d_in[0];
  const float* key   = (const float*)d_in[1];
  const float* value = (const float*)d_in[2];
  const int*   mask  = (const int*)d_in[3];
  const float* Wq    = (const float*)d_in[4];
  const float* bq    = (const float*)d_in[5];
  const float* Wk    = (const float*)d_in[6];
  const float* bk    = (const float*)d_in[7];
  const float* Wo    = (const float*)d_in[8];
  const float* bo    = (const float*)d_in[9];
  float* out = (float*)d_out;
  char* ws = (char*)d_ws;

  if (ws_size < (size_t)WS_NEED) return;  // diagnostic: leaves out == 0

  bf16* qp   = (bf16*)(ws + OFF_QP);
  bf16* kp   = (bf16*)(ws + OFF_KP);
  bf16* mvfB = (bf16*)(ws + OFF_MVFB);
  bf16* WoT  = (bf16*)(ws + OFF_WOT);
  float* ndp = (float*)(ws + OFF_NDP);

  prep_kernel<<<801, 256, 0, stream>>>(query, key, value, mask, Wq, bq, Wk, bk,
                                       Wo, qp, kp, mvfB, WoT);
  attn_kernel<<<512, 256, 0, stream>>>(qp, kp, mvfB, ndp);
  out_kernel<<<256, 256, 0, stream>>>(ndp, WoT, bo, out);
}

// Round 8
// 127.236 us; speedup vs baseline: 1.1052x; 1.0306x over previous
//
#include <hip/hip_runtime.h>
#include <hip/hip_bf16.h>
#include <math.h>

typedef __bf16 bf16;
typedef bf16 bf16x4 __attribute__((ext_vector_type(4)));
typedef bf16 bf16x8 __attribute__((ext_vector_type(8)));
typedef float f32x4 __attribute__((ext_vector_type(4)));
typedef float f32x16 __attribute__((ext_vector_type(16)));

#define B_   16
#define LQ_  256
#define LK_  4096
#define E_   64
#define H_   4
#define EK_  16
#define D_   32
#define LAT_ 32

// ws layout (bytes)
#define OFF_QP    0u          // bf16 [16][256][64]              = 512 KB
#define OFF_KP    524288u     // bf16 [16][4096][64]             = 8 MB
#define OFF_MVFB  8912896u    // bf16 [16][128][4][64][8] frag-ready = 8 MB
#define OFF_WOT   17301504u   // bf16 [32][128]                  = 8 KB
#define OFF_NDP   17309696u   // f32  [8 kc][16 b][4 h][256 q][64] = 33.5 MB (num 0..31, den 32..63)
#define WS_NEED   50864128u

#define LOG2E 1.44269504f

__device__ inline f32x4 mfma_bf16(bf16x8 a, bf16x8 b, f32x4 c) {
  return __builtin_amdgcn_mfma_f32_16x16x32_bf16(a, b, c, 0, 0, 0);
}
__device__ inline f32x16 mfma_bf16_32(bf16x8 a, bf16x8 b, f32x16 c) {
  return __builtin_amdgcn_mfma_f32_32x32x16_bf16(a, b, c, 0, 0, 0);
}

// ---------------------------------------------------------------------------
// Kernel 0: prep.  blocks [0,32): q-proj, [32,544): k-proj, [544,800): mvfB,
// [800]: WoT.  Proj = MFMA GEMM rows x (64x64) W, +bias; q scaled by
// 0.25*log2e (folds 1/sqrt(ek) and the exp->exp2 conversion).
// ---------------------------------------------------------------------------
__global__ __launch_bounds__(256) void prep_kernel(
    const float* __restrict__ query, const float* __restrict__ key,
    const float* __restrict__ value, const int* __restrict__ mask,
    const float* __restrict__ Wq, const float* __restrict__ bq,
    const float* __restrict__ Wk, const float* __restrict__ bk,
    const float* __restrict__ Wo,
    bf16* __restrict__ qp, bf16* __restrict__ kp,
    bf16* __restrict__ mvfB, bf16* __restrict__ WoT)
{
  __shared__ __align__(16) bf16 s_b[16896];  // 33792 B, unioned across roles
  const int bid = blockIdx.x;
  const int tid = threadIdx.x;

  if (bid < 544) {
    // ---- projection role: 128 rows per block ----
    const bool isQ = bid < 32;
    const int row0 = isQ ? bid * 128 : (bid - 32) * 128;
    const float* in   = isQ ? query : key;
    const float* W    = isQ ? Wq : Wk;
    const float* bias = isQ ? bq : bk;
    bf16* outp        = isQ ? qp : kp;
    const float scal  = isQ ? (0.25f * LOG2E) : 1.0f;

    bf16* sIn = s_b;          // [128][72]
    bf16* sWT = s_b + 9216;   // [64][72]  (W^T: [col][k])

#pragma unroll
    for (int p = 0; p < 8; ++p) {
      int f4 = tid + p * 256;            // 2048 float4
      int row = f4 >> 4, e4 = (f4 & 15) * 4;
      float4 v = *(const float4*)(in + (size_t)(row0 + row) * 64 + e4);
      bf16x4 b4;
      b4[0] = (bf16)v.x; b4[1] = (bf16)v.y; b4[2] = (bf16)v.z; b4[3] = (bf16)v.w;
      *(bf16x4*)(sIn + row * 72 + e4) = b4;
    }
#pragma unroll
    for (int p = 0; p < 4; ++p) {
      int f4 = tid + p * 256;            // 1024 float4
      int k = f4 >> 4, c4 = (f4 & 15) * 4;
      float4 v = *(const float4*)(W + k * 64 + c4);
      sWT[(c4 + 0) * 72 + k] = (bf16)v.x;
      sWT[(c4 + 1) * 72 + k] = (bf16)v.y;
      sWT[(c4 + 2) * 72 + k] = (bf16)v.z;
      sWT[(c4 + 3) * 72 + k] = (bf16)v.w;
    }
    __syncthreads();

    const int w = tid >> 6, l = tid & 63, l15 = l & 15, g = l >> 4;
    f32x4 acc[2][4];
#pragma unroll
    for (int mt = 0; mt < 2; ++mt)
#pragma unroll
      for (int nt = 0; nt < 4; ++nt) acc[mt][nt] = f32x4{0.f, 0.f, 0.f, 0.f};

#pragma unroll
    for (int ks = 0; ks < 2; ++ks) {
      bf16x8 A0 = *(bf16x8*)(sIn + (32 * w + l15) * 72 + 32 * ks + 8 * g);
      bf16x8 A1 = *(bf16x8*)(sIn + (32 * w + 16 + l15) * 72 + 32 * ks + 8 * g);
#pragma unroll
      for (int nt = 0; nt < 4; ++nt) {
        bf16x8 Bf = *(bf16x8*)(sWT + (16 * nt + l15) * 72 + 32 * ks + 8 * g);
        acc[0][nt] = mfma_bf16(A0, Bf, acc[0][nt]);
        acc[1][nt] = mfma_bf16(A1, Bf, acc[1][nt]);
      }
    }
#pragma unroll
    for (int mt = 0; mt < 2; ++mt)
#pragma unroll
      for (int nt = 0; nt < 4; ++nt) {
        int col = 16 * nt + l15;
        float bv = bias[col];
#pragma unroll
        for (int r = 0; r < 4; ++r) {
          int row = row0 + 32 * w + 16 * mt + 4 * g + r;
          outp[(size_t)row * 64 + col] = (bf16)((acc[mt][nt][r] + bv) * scal);
        }
      }
  } else if (bid < 800) {
    // ---- mvfB role: 256-kk chunk -> bf16, B-frag-ready tiled layout ----
    // element (b,col,kk): tile=kk>>5, nt=col>>4, lane=16*((kk>>3)&3)+(col&15),
    // j=kk&7 -> flat (((b*128+tile)*4+nt)*64+lane)*8+j
    const int rb = bid - 544;
    const int b = rb >> 4, kk0 = (rb & 15) * 256;
    // s_b as [col 64][kk 256 pad 264]
#pragma unroll
    for (int p = 0; p < 8; ++p) {
      int f4 = tid + p * 256;            // 2048 vec4 over [256 kk][32 d]
      int kk = f4 >> 3, d4 = (f4 & 7) * 4;
      size_t gi = ((size_t)(b * LK_ + kk0 + kk)) * 32 + d4;
      float4 v = *(const float4*)(value + gi);
      int4   m = *(const int4*)(mask + gi);
      s_b[(d4 + 0) * 264 + kk] = (bf16)(m.x ? v.x : 0.0f);
      s_b[(d4 + 1) * 264 + kk] = (bf16)(m.y ? v.y : 0.0f);
      s_b[(d4 + 2) * 264 + kk] = (bf16)(m.z ? v.z : 0.0f);
      s_b[(d4 + 3) * 264 + kk] = (bf16)(m.w ? v.w : 0.0f);
      s_b[(32 + d4 + 0) * 264 + kk] = (bf16)(float)m.x;
      s_b[(32 + d4 + 1) * 264 + kk] = (bf16)(float)m.y;
      s_b[(32 + d4 + 2) * 264 + kk] = (bf16)(float)m.z;
      s_b[(32 + d4 + 3) * 264 + kk] = (bf16)(float)m.w;
    }
    __syncthreads();
    // writeback: thread owns col = tid>>2, kk range [seg*64, seg*64+64)
    const int col = tid >> 2, seg = tid & 3;
    const int nt = col >> 4, l15c = col & 15;
#pragma unroll
    for (int w2 = 0; w2 < 8; ++w2) {
      int kkg = seg * 64 + w2 * 8;                 // 8-aligned
      int tile = (kk0 + kkg) >> 5;
      int gq = (kkg >> 3) & 3;
      int lane = 16 * gq + l15c;
      uint4 d = *(uint4*)(s_b + col * 264 + kkg);
      *(uint4*)(mvfB + (size_t)((((b * 128 + tile) * 4 + nt) * 64 + lane)) * 8) = d;
    }
  } else {
    // ---- WoT role: Wo[128][32] -> WoT[32][128] bf16 ----
#pragma unroll
    for (int p = 0; p < 16; ++p) {
      int f = tid + p * 256;
      int k = f >> 5, n = f & 31;
      WoT[n * 128 + k] = (bf16)Wo[f];
    }
  }
}

// ---------------------------------------------------------------------------
// Kernel 1: attention — R4 structure (q32, grid 1024, barrier/atomic-free),
// scores upgraded to ONE 32x32x16 MFMA (K=16 exact: no zero-padded K half,
// no idle half-wave on kA/qB loads). D-layout (m101): col=lane&31 = q,
// row kk = (reg&3)+8*(reg>>2)+4*(lane>>5) -> 4 consecutive kk per reg-quad
// -> same b64 LDS write / b128 read path as R4. PV: 8x 16x16x32 vs mvfB.
// ---------------------------------------------------------------------------
__global__ __launch_bounds__(256, 4) void attn_kernel(
    const bf16* __restrict__ qp, const bf16* __restrict__ kp,
    const bf16* __restrict__ mvfB, float* __restrict__ ndp)
{
  __shared__ __align__(16) bf16 s_se[4 * 1280];   // [wave][q 32 stride 40][kk 32]

  const int bid = blockIdx.x;
  const int kc = bid & 7, qt = (bid >> 3) & 7, b = bid >> 6;
  const int tid = threadIdx.x;
  const int h = tid >> 6, l = tid & 63, l15 = l & 15, g = l >> 4;
  const int l31 = l & 31, hi = l >> 5;
  const int q0 = qt * 32;
  const int tile0 = kc * 16;   // tiles of 32 kk; 16 per block

  // persistent Q B-frag for 32x32x16: B[k=e][n=q], lane: n=l31, k=8*hi+j
  bf16x8 qB = *(const bf16x8*)(qp + (size_t)((b * LQ_ + q0 + l31) * 64 + h * EK_ + hi * 8));

  f32x4 acc[2][4];
#pragma unroll
  for (int mt = 0; mt < 2; ++mt)
#pragma unroll
    for (int nt = 0; nt < 4; ++nt) acc[mt][nt] = f32x4{0.f, 0.f, 0.f, 0.f};

  bf16* se_w = s_se + h * 1280;
  const bf16* mvt0 = mvfB + (size_t)(b * 128 + tile0) * 2048;  // 4*64*8 per tile
  const bf16* kp_b = kp + (size_t)(b * LK_ + tile0 * 32) * 64 + h * EK_ + hi * 8;

#pragma unroll 2
  for (int t = 0; t < 16; ++t) {
    const bf16* mvt = mvt0 + (size_t)t * 2048;

    // global loads -> regs (no LDS staging, no barriers, no divergence)
    bf16x8 mvB[4];
#pragma unroll
    for (int nt = 0; nt < 4; ++nt)
      mvB[nt] = *(const bf16x8*)(mvt + (nt * 64 + l) * 8);

    // kA for 32x32x16: A[m=kk][k=e], lane: m=l31, k=8*hi+j — full wave
    bf16x8 kA = *(const bf16x8*)(kp_b + (size_t)(t * 32 + l31) * 64);

    // transposed scores: one 32x32x16 MFMA, S^T[kk 32][q 32], K=16 exact
    f32x16 S;
#pragma unroll
    for (int i = 0; i < 16; ++i) S[i] = 0.f;
    S = mfma_bf16_32(kA, qB, S);

    // exp2 (log2e folded into qp) -> bf16, packed b64 writes
    // reg = 4*rq + r -> kk = 8*rq + 4*hi + r (4 consecutive kk per quad)
#pragma unroll
    for (int rq = 0; rq < 4; ++rq) {
      bf16x4 e4;
#pragma unroll
      for (int r = 0; r < 4; ++r) e4[r] = (bf16)exp2f(S[4 * rq + r]);
      *(bf16x4*)(se_w + l31 * 40 + 8 * rq + 4 * hi) = e4;
    }

    // ordering fence for the same-wave LDS round-trip (no barrier needed)
    asm volatile("" ::: "memory");

    // PV: A-frags from wave-private LDS (A[q=l15][kk=8g+j]), 8 MFMAs
#pragma unroll
    for (int mq = 0; mq < 2; ++mq) {
      bf16x8 eA = *(bf16x8*)(se_w + (16 * mq + l15) * 40 + 8 * g);
#pragma unroll
      for (int nt = 0; nt < 4; ++nt)
        acc[mq][nt] = mfma_bf16(eA, mvB[nt], acc[mq][nt]);
    }
  }

  // epilogue: plain stores of this block's kc-partial (disjoint slice)
  float* ndp_w = ndp + ((((size_t)kc * B_ + b) * H_ + h) * LQ_) * 64;
#pragma unroll
  for (int mt = 0; mt < 2; ++mt)
#pragma unroll
    for (int nt = 0; nt < 4; ++nt)
#pragma unroll
      for (int r = 0; r < 4; ++r) {
        int q = q0 + 16 * mt + 4 * g + r;
        int col = 16 * nt + l15;
        ndp_w[(size_t)q * 64 + col] = acc[mt][nt][r];
      }
}

// ---------------------------------------------------------------------------
// Kernel 2: reduce 8 kc-partials, x = num/den -> bf16 -> out = x @ Wo + bo.
// grid 256 (b, 16-q tile).
// ---------------------------------------------------------------------------
__global__ __launch_bounds__(256) void out_kernel(
    const float* __restrict__ ndp, const bf16* __restrict__ WoT,
    const float* __restrict__ bo, float* __restrict__ out)
{
  __shared__ __align__(16) bf16 s_x[16 * 136];  // [q 16][j 128 pad 136]
  const int bid = blockIdx.x;
  const int b = bid >> 4, q0 = (bid & 15) * 16;
  const int tid = threadIdx.x;
  const int q = tid >> 4, jg = tid & 15;
  const int h = jg >> 2, d0 = (jg & 3) * 8;

  f32x4 nlo = f32x4{0.f,0.f,0.f,0.f}, nhi = f32x4{0.f,0.f,0.f,0.f};
  f32x4 dlo = f32x4{0.f,0.f,0.f,0.f}, dhi = f32x4{0.f,0.f,0.f,0.f};
#pragma unroll
  for (int kc = 0; kc < 8; ++kc) {
    const float* p = ndp + ((((size_t)kc * B_ + b) * H_ + h) * LQ_ + q0 + q) * 64;
    nlo += *(const f32x4*)(p + d0);
    nhi += *(const f32x4*)(p + d0 + 4);
    dlo += *(const f32x4*)(p + 32 + d0);
    dhi += *(const f32x4*)(p + 32 + d0 + 4);
  }
  bf16* sx = s_x + q * 136 + h * 32 + d0;
#pragma unroll
  for (int i = 0; i < 4; ++i) {
    sx[i]     = (bf16)(nlo[i] / dlo[i]);
    sx[4 + i] = (bf16)(nhi[i] / dhi[i]);
  }
  __syncthreads();
  const int w = tid >> 6, l = tid & 63, l15 = l & 15, g = l >> 4;
  if (w < 2) {
    const int nt = w;
    f32x4 acc = f32x4{0.f, 0.f, 0.f, 0.f};
#pragma unroll
    for (int ks = 0; ks < 4; ++ks) {
      bf16x8 A  = *(bf16x8*)(s_x + l15 * 136 + 32 * ks + 8 * g);
      bf16x8 Bf = *(const bf16x8*)(WoT + (l15 + 16 * nt) * 128 + 32 * ks + 8 * g);
      acc = mfma_bf16(A, Bf, acc);
    }
    float bv = bo[l15 + 16 * nt];
#pragma unroll
    for (int r = 0; r < 4; ++r) {
      int row = q0 + 4 * g + r;
      out[(size_t)(b * LQ_ + row) * LAT_ + l15 + 16 * nt] = acc[r] + bv;
    }
  }
}

extern "C" void kernel_launch(void* const* d_in, const int* in_sizes, int n_in,
                              void* d_out, int out_size, void* d_ws, size_t ws_size,
                              hipStream_t stream) {
  const float* query = (const float*)d_in[0];
  const float* key   = (const float*)d_in[1];
  const float* value = (const float*)d_in[2];
  const int*   mask  = (const int*)d_in[3];
  const float* Wq    = (const float*)d_in[4];
  const float* bq    = (const float*)d_in[5];
  const float* Wk    = (const float*)d_in[6];
  const float* bk    = (const float*)d_in[7];
  const float* Wo    = (const float*)d_in[8];
  const float* bo    = (const float*)d_in[9];
  float* out = (float*)d_out;
  char* ws = (char*)d_ws;

  if (ws_size < (size_t)WS_NEED) return;  // diagnostic: leaves out == 0

  bf16* qp   = (bf16*)(ws + OFF_QP);
  bf16* kp   = (bf16*)(ws + OFF_KP);
  bf16* mvfB = (bf16*)(ws + OFF_MVFB);
  bf16* WoT  = (bf16*)(ws + OFF_WOT);
  float* ndp = (float*)(ws + OFF_NDP);

  prep_kernel<<<801, 256, 0, stream>>>(query, key, value, mask, Wq, bq, Wk, bk,
                                       Wo, qp, kp, mvfB, WoT);
  attn_kernel<<<1024, 256, 0, stream>>>(qp, kp, mvfB, ndp);
  out_kernel<<<256, 256, 0, stream>>>(ndp, WoT, bo, out);
}